// Round 1
// baseline (7747.713 us; speedup 1.0000x reference)
//
#include <hip/hip_runtime.h>

#define E 256
#define KSMP 128

typedef float f32x4 __attribute__((ext_vector_type(4)));

__device__ __forceinline__ unsigned pack_fp8x4(float a, float b, float c, float d) {
    int v = __builtin_amdgcn_cvt_pk_fp8_f32(a, b, 0, false);
    v = __builtin_amdgcn_cvt_pk_fp8_f32(c, d, v, true);
    return (unsigned)v;
}

// acc[fot] += A(weights from LDS) * B(activation quads via cross-lane permute)
__device__ __forceinline__ void mm_fp8(f32x4 (&acc)[16], const unsigned char* abase,
                                       const unsigned (&q)[16], int addrB0, int addrB1,
                                       bool lowhalf) {
    #pragma unroll
    for (int kc = 0; kc < 8; ++kc) {
        int t00 = __builtin_amdgcn_ds_bpermute(addrB0, (int)q[2*kc]);
        int t01 = __builtin_amdgcn_ds_bpermute(addrB0, (int)q[2*kc+1]);
        int t10 = __builtin_amdgcn_ds_bpermute(addrB1, (int)q[2*kc]);
        int t11 = __builtin_amdgcn_ds_bpermute(addrB1, (int)q[2*kc+1]);
        unsigned b0 = lowhalf ? (unsigned)t00 : (unsigned)t01;
        unsigned b1 = lowhalf ? (unsigned)t10 : (unsigned)t11;
        long B = (long)(((unsigned long long)b1 << 32) | (unsigned long long)b0);
        #pragma unroll
        for (int fot = 0; fot < 16; ++fot) {
            long A = *(const long*)(abase + kc*8192 + fot*128);
            acc[fot] = __builtin_amdgcn_mfma_f32_16x16x32_fp8_fp8(A, B, acc[fot], 0, 0, 0);
        }
    }
}

__global__ __launch_bounds__(512, 2) void cnf_kernel(
    const float* __restrict__ h, const float* __restrict__ emb, const int* __restrict__ tgts,
    const float* __restrict__ Wx, const float* __restrict__ wx_t, const float* __restrict__ bx,
    const float* __restrict__ Wh, const float* __restrict__ wh_t, const float* __restrict__ bh,
    const float* __restrict__ W2, const float* __restrict__ b2, float* __restrict__ out)
{
    // weights, fp8, layout [kchunk c=k/8][f][k%8]  (A-operand ready)
    __shared__ __align__(16) unsigned char lds_wx[65536];
    __shared__ __align__(16) unsigned char lds_w2[65536];
    __shared__ __align__(16) float lds_h[E];
    __shared__ __align__(16) float lds_ht[E];   // h@Wh^T + bx + bh (per-block: one n)
    __shared__ __align__(16) float lds_wt[E];   // wx_t + wh_t
    __shared__ __align__(16) float lds_d[E];    // trace diag: d[f] = sum_i W2[i][f]*Wx[f][i]
    __shared__ __align__(16) float lds_b2[E];

    const int tid = threadIdx.x;
    const int n   = blockIdx.x;
    const int l   = tid & 63;
    const int w   = tid >> 6;
    const int lg  = l >> 4;
    const int lm  = l & 15;

    // ---------- phase 0: small vectors ----------
    if (tid < 64) ((f32x4*)lds_h)[tid] = ((const f32x4*)(h + n*E))[tid];
    if (tid < 256) { lds_wt[tid] = wx_t[tid] + wh_t[tid]; lds_b2[tid] = b2[tid]; }
    __syncthreads();

    // ---------- phase 1: ht/d (threads 0-255) + fp8 weight staging (threads 256-511) ----------
    if (tid < 256) {
        const int f = tid;
        const float* whr = Wh + f*E;
        const float* wxr = Wx + f*E;
        float acch = 0.f, accd = 0.f;
        #pragma unroll 4
        for (int i = 0; i < E; ++i) {
            acch += whr[i] * lds_h[i];
            accd += W2[i*E + f] * wxr[i];
        }
        lds_ht[f] = acch + bx[f] + bh[f];
        lds_d[f]  = accd;
    } else {
        const int f = tid - 256;
        const float* wxr = Wx + f*E;
        const float* w2r = W2 + f*E;
        #pragma unroll 2
        for (int c = 0; c < 32; ++c) {
            f32x4 a = *(const f32x4*)(wxr + c*8);
            f32x4 b = *(const f32x4*)(wxr + c*8 + 4);
            unsigned w0 = pack_fp8x4(a[0], a[1], a[2], a[3]);
            unsigned w1 = pack_fp8x4(b[0], b[1], b[2], b[3]);
            *(unsigned long long*)(lds_wx + (c*256 + f)*8) =
                ((unsigned long long)w1 << 32) | w0;
            a = *(const f32x4*)(w2r + c*8);
            b = *(const f32x4*)(w2r + c*8 + 4);
            w0 = pack_fp8x4(a[0], a[1], a[2], a[3]);
            w1 = pack_fp8x4(b[0], b[1], b[2], b[3]);
            *(unsigned long long*)(lds_w2 + (c*256 + f)*8) =
                ((unsigned long long)w1 << 32) | w0;
        }
    }
    __syncthreads();
    // After this point: no barriers, waves fully independent.

    // ---------- z0 gather + log p(z0) ----------
    f32x4 zb[16], ks[16];
    unsigned qx[16];
    const int sOut = n*KSMP + (w << 4) + lm;
    const int tgt  = tgts[sOut];
    const float* z0p = emb + (size_t)tgt * E;
    float ssq = 0.f;
    #pragma unroll
    for (int ft = 0; ft < 16; ++ft) {
        const int f0 = ft*16 + lg*4;
        f32x4 z = *(const f32x4*)(z0p + f0);
        zb[ft] = z;
        f32x4 hv = *(const f32x4*)(lds_h + f0);
        #pragma unroll
        for (int r = 0; r < 4; ++r) { float dd = z[r] - hv[r]; ssq += dd*dd; }
        qx[ft] = pack_fp8x4(z[0], z[1], z[2], z[3]);
    }
    ssq += __shfl_xor(ssq, 16);
    ssq += __shfl_xor(ssq, 32);
    const float lp0 = -0.5f*ssq - 235.2482645f;   // (E/2)*ln(2*pi)

    // cross-lane permute addresses for C-layout quads -> B-operand
    const int addrB0 = 4 * (lm + 16*((2*lg) & 3));
    const int addrB1 = 4 * (lm + 16*((2*lg + 1) & 3));
    const unsigned char* wxbase = lds_wx + (lg*256 + lm)*8;
    const unsigned char* w2base = lds_w2 + (lg*256 + lm)*8;
    const bool lowhalf = (lg < 2);

    const float dt = 0.125f;
    float lpacc = 0.f;

    for (int step = 0; step < 8; ++step) {
        const float t0 = step * dt;
        for (int e = 0; e < 4; ++e) {
            const float te = t0 + ((e == 0) ? 0.f : (e == 3) ? dt : 0.5f*dt);
            f32x4 acc[16];
            #pragma unroll
            for (int i = 0; i < 16; ++i) acc[i] = (f32x4){0.f, 0.f, 0.f, 0.f};
            mm_fp8(acc, wxbase, qx, addrB0, addrB1, lowhalf);   // pre' = Wx * zs^T

            float trp = 0.f;
            #pragma unroll
            for (int ft = 0; ft < 16; ++ft) {
                const int f0 = ft*16 + lg*4;
                f32x4 htq = *(const f32x4*)(lds_ht + f0);
                f32x4 wtq = *(const f32x4*)(lds_wt + f0);
                f32x4 dq  = *(const f32x4*)(lds_d + f0);
                float sp[4];
                #pragma unroll
                for (int r = 0; r < 4; ++r) {
                    float x  = acc[ft][r] + htq[r] + te*wtq[r];
                    float ee = __builtin_amdgcn_exp2f(fabsf(x) * -1.442695041f); // e^{-|x|}
                    // ln(1+t), t in (0,1]: A&S 4.1.43, |err|<=1e-5
                    float lg1p = ee*(0.99949556f + ee*(-0.49190896f + ee*(0.28947478f +
                                 ee*(-0.13606275f + ee*0.03215845f))));
                    sp[r] = fmaxf(x, 0.f) + lg1p;                 // softplus
                    float rr = __builtin_amdgcn_rcpf(1.f + ee);
                    float sg = (x >= 0.f) ? rr : 1.f - rr;        // sigmoid
                    trp += sg * dq[r];
                }
                qx[ft] = pack_fp8x4(sp[0], sp[1], sp[2], sp[3]);
            }

            #pragma unroll
            for (int i = 0; i < 16; ++i) acc[i] = (f32x4){0.f, 0.f, 0.f, 0.f};
            mm_fp8(acc, w2base, qx, addrB0, addrB1, lowhalf);    // dz' = W2 * softplus^T

            const float we = (e == 0 || e == 3) ? 1.f : 2.f;
            lpacc += we * trp;
            const float ce = (e == 2) ? dt : 0.5f*dt;
            #pragma unroll
            for (int ft = 0; ft < 16; ++ft) {
                const int f0 = ft*16 + lg*4;
                f32x4 b2q = *(const f32x4*)(lds_b2 + f0);
                float z4[4];
                #pragma unroll
                for (int r = 0; r < 4; ++r) {
                    float k = acc[ft][r] + b2q[r];
                    if (e == 0) ks[ft][r] = k; else ks[ft][r] += we*k;
                    float zsv;
                    if (e < 3) {
                        zsv = zb[ft][r] + ce*k;
                    } else {
                        zb[ft][r] += (dt/6.f) * ks[ft][r];
                        zsv = zb[ft][r];
                    }
                    z4[r] = zsv;
                }
                qx[ft] = pack_fp8x4(z4[0], z4[1], z4[2], z4[3]);
            }
        }
    }

    float lptot = lpacc;
    lptot += __shfl_xor(lptot, 16);
    lptot += __shfl_xor(lptot, 32);
    const float res = lp0 - (dt/6.f)*lptot;
    if (l < 16) out[sOut] = res;
}

extern "C" void kernel_launch(void* const* d_in, const int* in_sizes, int n_in,
                              void* d_out, int out_size, void* d_ws, size_t ws_size,
                              hipStream_t stream) {
    const float* h    = (const float*)d_in[0];
    const float* emb  = (const float*)d_in[1];
    const int*   tg   = (const int*)d_in[2];
    const float* Wx   = (const float*)d_in[3];
    const float* wx_t = (const float*)d_in[4];
    const float* bx   = (const float*)d_in[5];
    const float* Wh   = (const float*)d_in[6];
    const float* wh_t = (const float*)d_in[7];
    const float* bh   = (const float*)d_in[8];
    const float* W2   = (const float*)d_in[9];
    const float* b2   = (const float*)d_in[10];
    cnf_kernel<<<dim3(512), dim3(512), 0, stream>>>(h, emb, tg, Wx, wx_t, bx, Wh, wh_t, bh,
                                                    W2, b2, (float*)d_out);
}